// Round 1
// 920.414 us; speedup vs baseline: 1.2670x; 1.2670x over previous
//
#include <hip/hip_runtime.h>

// CrissCrossAttention on MI355X (gfx950). fp32 I/O.
// q/k path in split-bf16 (hi+lo, 3-MFMA products) for fp32-grade energies;
// v path in plain bf16. B=8, C=512, CQ=64, H=W=128.
//
//  K0:  weights -> wqk hi/lo bf16 [m][c] (m<128), wv bf16 [m][c] (m<512)
//  K1qk: q,k projection, split-bf16 x and W -> qh,ql,kh,kl (B,H,W,CQ) bf16
//        + writes xh (B,H,W,C) bf16 (hi split of x, transposed) into d_out scratch
//  K1v:  v projection from xh (pure bf16 GEMM, no transpose/convert) -> vt (B,W,H,C)
//  K2:  e_W[b,h,w,v] = q.k (split, 3 MFMAs) -> ew (B,W,H,W) fp32
//  K3a: per (b,w): e_H (split MFMA) + ew slice -> joint softmax ->
//       aH (B,W,H,H) bf16, aW (B,H,W,W) bf16
//  K3b: out_H -> oh (B,W,H,C) bf16
//  K4:  out_W + GAMMA*(oh+ow) + x -> out (B,C,H,W) fp32
//
// Bank-conflict fixes this round:
//  - k1_qk B staging (fp32->split transpose): scalar u16 writes were 16-way
//    conflicted (row stride 144 B, 144*8m % 128 == 0). XOR-swizzle col with
//    ((row>>3)&7)<<3 -> 2-way (free). Same XOR applied on fragment reads.
//  - k1_v: conflicts removed entirely by consuming pre-transposed xh.
//  - k3b/k4 Al staging (vt transpose): same 16-way pattern (stride 272 B),
//    XOR-swizzle col with ((row>>3)&15)<<3.

#define Bn 8
#define Cn 512
#define CQn 64
#define Hn 128
#define Wn 128
#define HWn (Hn*Wn)
#define GAMMA_F 1.0f

typedef __attribute__((ext_vector_type(8))) short short8;
typedef __attribute__((ext_vector_type(4))) float f32x4;
typedef unsigned short u16;
typedef unsigned int u32;

__device__ __forceinline__ float b2f(u16 h) {
    union { u32 u; float f; } v; v.u = ((u32)h) << 16; return v.f;
}
__device__ __forceinline__ u16 f2b(float f) {
    union { float f; u32 u; } v; v.f = f;
    u32 u = v.u;
    return (u16)((u + 0x7fffu + ((u >> 16) & 1u)) >> 16);  // RNE
}

#define MFMA(acc, a, b) acc = __builtin_amdgcn_mfma_f32_16x16x32_bf16(a, b, acc, 0, 0, 0)

// ---------------------------------------------------------------- K0
__global__ __launch_bounds__(256) void k0_wt(const float* __restrict__ wq,
                                             const float* __restrict__ wk,
                                             const float* __restrict__ wv,
                                             u16* __restrict__ wqkh, u16* __restrict__ wqkl,
                                             u16* __restrict__ wvt) {
    int idx = blockIdx.x * 256 + threadIdx.x;  // 128*512 + 512*512
    if (idx >= 128 * 512 + 512 * 512) return;
    if (idx < 128 * 512) {
        int m = idx >> 9, c = idx & 511;
        float v = (m < 64) ? wq[c * 64 + m] : wk[c * 64 + (m - 64)];
        u16 hi = f2b(v);
        wqkh[idx] = hi;
        wqkl[idx] = f2b(v - b2f(hi));
    } else {
        int j = idx - 128 * 512;
        int m = j >> 9, c = j & 511;
        wvt[j] = f2b(wv[c * 512 + m]);
    }
}

// ---------------------------------------------------------------- K1qk
// per (b,h): D[m,w] = sum_c Wqk[m,c] x[b,c,h,w], m in [0,128) = [q|k]
// split-bf16 both operands: acc = Ah*Bh + Ah*Bl + Al*Bh
// Also writes the staged hi-tile of x out to xh (B,H,W,C) for k1_v.
__global__ __launch_bounds__(256) void k1_qk(
    const float* __restrict__ x, const u16* __restrict__ wqkh, const u16* __restrict__ wqkl,
    const float* __restrict__ bq, const float* __restrict__ bk,
    u16* __restrict__ qh, u16* __restrict__ ql, u16* __restrict__ kh, u16* __restrict__ kl,
    u16* __restrict__ xh)
{
    __shared__ u16 Ahi[128 * 72];
    __shared__ u16 Alo[128 * 72];
    __shared__ u16 Bhi[128 * 72];
    __shared__ u16 Blo[128 * 72];
    int bid = blockIdx.x;
    int b = bid >> 7, h = bid & 127;
    int t = threadIdx.x;
    int lane = t & 63, wid = t >> 6;
    int quad = lane >> 4, l16 = lane & 15;
    int mw = (wid >> 1) * 64, nw = (wid & 1) * 64;

    f32x4 acc[4][4];
#pragma unroll
    for (int i = 0; i < 4; i++)
#pragma unroll
        for (int j = 0; j < 4; j++) acc[i][j] = (f32x4){0.f, 0.f, 0.f, 0.f};

    const float* xb = x + (size_t)b * Cn * HWn + (size_t)h * 128;
    u16* xhb = xh + ((size_t)(b * Hn + h)) * Wn * Cn;

    for (int ks = 0; ks < 8; ks++) {
        int c0 = ks * 64;
#pragma unroll
        for (int i = 0; i < 4; i++) {
            int chunk = i * 256 + t;            // 1024 chunks of 8
            int m = chunk >> 3, kq = chunk & 7;
            *(short8*)&Ahi[m * 72 + kq * 8] = *(const short8*)(wqkh + (size_t)m * 512 + c0 + kq * 8);
            *(short8*)&Alo[m * 72 + kq * 8] = *(const short8*)(wqkl + (size_t)m * 512 + c0 + kq * 8);
        }
#pragma unroll
        for (int i = 0; i < 4; i++) {
            int chunk = i * 256 + t;
            int kk = chunk >> 4, m = chunk & 15, n8 = m << 3;
            const float* src = xb + (size_t)(c0 + kk) * HWn + n8;
            float4 d0 = *(const float4*)(src);
            float4 d1 = *(const float4*)(src + 4);
            float f[8] = {d0.x, d0.y, d0.z, d0.w, d1.x, d1.y, d1.z, d1.w};
            int col = kk ^ ((m & 7) << 3);      // XOR-swizzle: kills 16-way write conflict
#pragma unroll
            for (int j = 0; j < 8; j++) {
                u16 hi = f2b(f[j]);
                Bhi[(n8 + j) * 72 + col] = hi;
                Blo[(n8 + j) * 72 + col] = f2b(f[j] - b2f(hi));
            }
        }
        __syncthreads();
#pragma unroll
        for (int k2 = 0; k2 < 64; k2 += 32) {
            short8 afh[4], afl[4], bfh[4], bfl[4];
#pragma unroll
            for (int mi = 0; mi < 4; mi++) {
                afh[mi] = *(const short8*)&Ahi[(mw + mi * 16 + l16) * 72 + k2 + quad * 8];
                afl[mi] = *(const short8*)&Alo[(mw + mi * 16 + l16) * 72 + k2 + quad * 8];
            }
#pragma unroll
            for (int ni = 0; ni < 4; ni++) {
                int wrow = nw + ni * 16 + l16;
                int col = (k2 + quad * 8) ^ (((wrow >> 3) & 7) << 3);
                bfh[ni] = *(const short8*)&Bhi[wrow * 72 + col];
                bfl[ni] = *(const short8*)&Blo[wrow * 72 + col];
            }
#pragma unroll
            for (int mi = 0; mi < 4; mi++)
#pragma unroll
                for (int ni = 0; ni < 4; ni++) {
                    MFMA(acc[mi][ni], afh[mi], bfh[ni]);
                    MFMA(acc[mi][ni], afh[mi], bfl[ni]);
                    MFMA(acc[mi][ni], afl[mi], bfh[ni]);
                }
        }
        // write staged hi-tile of x out (transposed, de-swizzled) -> xh[b][h][w][c]
#pragma unroll
        for (int p = 0; p < 4; p++) {
            int w = p * 32 + (t >> 3), kq = t & 7;
            int col = (kq * 8) ^ (((w >> 3) & 7) << 3);
            *(short8*)(xhb + (size_t)w * Cn + c0 + kq * 8) = *(const short8*)&Bhi[w * 72 + col];
        }
        __syncthreads();
    }

#pragma unroll
    for (int mi = 0; mi < 4; mi++) {
        int gm = mw + mi * 16 + quad * 4;   // 0..124, 4 consecutive channels
        float bias[4];
#pragma unroll
        for (int r = 0; r < 4; r++) {
            int g = gm + r;
            bias[r] = (g < 64) ? bq[g] : bk[g - 64];
        }
#pragma unroll
        for (int ni = 0; ni < 4; ni++) {
            int w = nw + ni * 16 + l16;
            u16 oh_[4], ol_[4];
#pragma unroll
            for (int r = 0; r < 4; r++) {
                float val = acc[mi][ni][r] + bias[r];
                oh_[r] = f2b(val);
                ol_[r] = f2b(val - b2f(oh_[r]));
            }
            uint2 ph, pl;
            ph.x = (u32)oh_[0] | ((u32)oh_[1] << 16);
            ph.y = (u32)oh_[2] | ((u32)oh_[3] << 16);
            pl.x = (u32)ol_[0] | ((u32)ol_[1] << 16);
            pl.y = (u32)ol_[2] | ((u32)ol_[3] << 16);
            size_t base = ((size_t)((b * Hn + h) * Wn + w)) * CQn;
            if (gm < 64) {
                *(uint2*)(qh + base + gm) = ph;
                *(uint2*)(ql + base + gm) = pl;
            } else {
                *(uint2*)(kh + base + gm - 64) = ph;
                *(uint2*)(kl + base + gm - 64) = pl;
            }
        }
    }
}

// ---------------------------------------------------------------- K1v
// per (b,mt,h): D[m,w] = sum_c Wv[m,c] xh[b,h,w,c] -> vt (B,W,H,C) bf16
// Pure bf16 GEMM: both operands staged with contiguous short8 copies.
__global__ __launch_bounds__(256) void k1_v(
    const u16* __restrict__ xh, const u16* __restrict__ wvt,
    const float* __restrict__ bv, u16* __restrict__ vt)
{
    __shared__ u16 Al[128 * 72];
    __shared__ u16 Bl[128 * 72];
    int bid = blockIdx.x;
    int b = bid / 512;
    int rem = bid % 512;
    int mt = rem >> 7, h = rem & 127;
    int t = threadIdx.x;
    int lane = t & 63, wid = t >> 6;
    int quad = lane >> 4, l16 = lane & 15;
    int mw = (wid >> 1) * 64, nw = (wid & 1) * 64;

    f32x4 acc[4][4];
#pragma unroll
    for (int i = 0; i < 4; i++)
#pragma unroll
        for (int j = 0; j < 4; j++) acc[i][j] = (f32x4){0.f, 0.f, 0.f, 0.f};

    const u16* xhb = xh + ((size_t)(b * Hn + h)) * Wn * Cn;
    const u16* wtm = wvt + (size_t)(mt * 128) * 512;

    for (int ks = 0; ks < 8; ks++) {
        int c0 = ks * 64;
#pragma unroll
        for (int i = 0; i < 4; i++) {
            int chunk = i * 256 + t;
            int m = chunk >> 3, kq = chunk & 7;
            *(short8*)&Al[m * 72 + kq * 8] = *(const short8*)(wtm + (size_t)m * 512 + c0 + kq * 8);
        }
#pragma unroll
        for (int i = 0; i < 4; i++) {
            int chunk = i * 256 + t;
            int w = chunk >> 3, kq = chunk & 7;
            *(short8*)&Bl[w * 72 + kq * 8] = *(const short8*)(xhb + (size_t)w * Cn + c0 + kq * 8);
        }
        __syncthreads();
#pragma unroll
        for (int k2 = 0; k2 < 64; k2 += 32) {
            short8 af[4], bf[4];
#pragma unroll
            for (int mi = 0; mi < 4; mi++)
                af[mi] = *(const short8*)&Al[(mw + mi * 16 + l16) * 72 + k2 + quad * 8];
#pragma unroll
            for (int ni = 0; ni < 4; ni++)
                bf[ni] = *(const short8*)&Bl[(nw + ni * 16 + l16) * 72 + k2 + quad * 8];
#pragma unroll
            for (int mi = 0; mi < 4; mi++)
#pragma unroll
                for (int ni = 0; ni < 4; ni++) MFMA(acc[mi][ni], af[mi], bf[ni]);
        }
        __syncthreads();
    }

#pragma unroll
    for (int mi = 0; mi < 4; mi++) {
        int gm = mt * 128 + mw + mi * 16 + quad * 4;
        float bias[4];
#pragma unroll
        for (int r = 0; r < 4; r++) bias[r] = bv[gm + r];
#pragma unroll
        for (int ni = 0; ni < 4; ni++) {
            int w = nw + ni * 16 + l16;
            u16 o[4];
#pragma unroll
            for (int r = 0; r < 4; r++) o[r] = f2b(acc[mi][ni][r] + bias[r]);
            uint2 p;
            p.x = (u32)o[0] | ((u32)o[1] << 16);
            p.y = (u32)o[2] | ((u32)o[3] << 16);
            *(uint2*)(vt + ((size_t)((b * Wn + w) * Hn + h)) * Cn + gm) = p;
        }
    }
}

// ---------------------------------------------------------------- K2
// D[v,w] = sum_d k_row[v,d] * q_row[w,d] (split) -> ew[((b*W+w)*H+h)*W + v]
__global__ __launch_bounds__(256) void k2_ew(
    const u16* __restrict__ qh, const u16* __restrict__ ql,
    const u16* __restrict__ kh, const u16* __restrict__ kl, float* __restrict__ ew)
{
    __shared__ u16 Akh[128 * 72];
    __shared__ u16 Akl[128 * 72];
    __shared__ u16 Bqh[128 * 72];
    __shared__ u16 Bql[128 * 72];
    int bid = blockIdx.x;
    int b = bid >> 7, h = bid & 127;
    int t = threadIdx.x;
    int lane = t & 63, wid = t >> 6;
    int quad = lane >> 4, l16 = lane & 15;
    int mw = (wid >> 1) * 64, nw = (wid & 1) * 64;

    size_t rowbase = ((size_t)(b * Hn + h)) * Wn * CQn;
#pragma unroll
    for (int i = 0; i < 4; i++) {
        int chunk = i * 256 + t;
        int row = chunk >> 3, kq = chunk & 7;
        size_t off = rowbase + row * 64 + kq * 8;
        *(short8*)&Akh[row * 72 + kq * 8] = *(const short8*)&kh[off];
        *(short8*)&Akl[row * 72 + kq * 8] = *(const short8*)&kl[off];
        *(short8*)&Bqh[row * 72 + kq * 8] = *(const short8*)&qh[off];
        *(short8*)&Bql[row * 72 + kq * 8] = *(const short8*)&ql[off];
    }
    __syncthreads();

    f32x4 acc[4][4];
#pragma unroll
    for (int i = 0; i < 4; i++)
#pragma unroll
        for (int j = 0; j < 4; j++) acc[i][j] = (f32x4){0.f, 0.f, 0.f, 0.f};
#pragma unroll
    for (int k2 = 0; k2 < 64; k2 += 32) {
        short8 afh[4], afl[4], bfh[4], bfl[4];
#pragma unroll
        for (int mi = 0; mi < 4; mi++) {
            afh[mi] = *(const short8*)&Akh[(mw + mi * 16 + l16) * 72 + k2 + quad * 8];
            afl[mi] = *(const short8*)&Akl[(mw + mi * 16 + l16) * 72 + k2 + quad * 8];
        }
#pragma unroll
        for (int ni = 0; ni < 4; ni++) {
            bfh[ni] = *(const short8*)&Bqh[(nw + ni * 16 + l16) * 72 + k2 + quad * 8];
            bfl[ni] = *(const short8*)&Bql[(nw + ni * 16 + l16) * 72 + k2 + quad * 8];
        }
#pragma unroll
        for (int mi = 0; mi < 4; mi++)
#pragma unroll
            for (int ni = 0; ni < 4; ni++) {
                MFMA(acc[mi][ni], afh[mi], bfh[ni]);
                MFMA(acc[mi][ni], afh[mi], bfl[ni]);
                MFMA(acc[mi][ni], afl[mi], bfh[ni]);
            }
    }
#pragma unroll
    for (int mi = 0; mi < 4; mi++) {
        int v0 = mw + mi * 16 + quad * 4;
#pragma unroll
        for (int ni = 0; ni < 4; ni++) {
            int w = nw + ni * 16 + l16;
            *(f32x4*)(ew + ((size_t)((b * Wn + w) * Hn + h)) * Wn + v0) = acc[mi][ni];
        }
    }
}

// ---------------------------------------------------------------- K3a
// per (b,w): e_H[g,h] split MFMA, diag mask, joint softmax with ew slice
__global__ __launch_bounds__(256) void k3a_soft(
    const u16* __restrict__ qh, const u16* __restrict__ ql,
    const u16* __restrict__ kh, const u16* __restrict__ kl,
    const float* __restrict__ ew, u16* __restrict__ aH, u16* __restrict__ aW)
{
    __shared__ char smem[73728];             // 4 staging tiles, then e[h][132] fp32
    u16* Akh = (u16*)smem;
    u16* Akl = (u16*)(smem + 18432);
    u16* Bqh = (u16*)(smem + 36864);
    u16* Bql = (u16*)(smem + 55296);
    float* el = (float*)smem;

    int bid = blockIdx.x;
    int b = bid >> 7, w = bid & 127;
    int t = threadIdx.x;
    int lane = t & 63, wid = t >> 6;
    int quad = lane >> 4, l16 = lane & 15;
    int mw = (wid >> 1) * 64, nw = (wid & 1) * 64;

#pragma unroll
    for (int i = 0; i < 4; i++) {
        int chunk = i * 256 + t;
        int row = chunk >> 3, kq = chunk & 7;
        size_t off = ((size_t)((b * Hn + row) * Wn + w)) * CQn + kq * 8;
        *(short8*)&Akh[row * 72 + kq * 8] = *(const short8*)&kh[off];
        *(short8*)&Akl[row * 72 + kq * 8] = *(const short8*)&kl[off];
        *(short8*)&Bqh[row * 72 + kq * 8] = *(const short8*)&qh[off];
        *(short8*)&Bql[row * 72 + kq * 8] = *(const short8*)&ql[off];
    }
    __syncthreads();

    f32x4 acc[4][4];
#pragma unroll
    for (int i = 0; i < 4; i++)
#pragma unroll
        for (int j = 0; j < 4; j++) acc[i][j] = (f32x4){0.f, 0.f, 0.f, 0.f};
#pragma unroll
    for (int k2 = 0; k2 < 64; k2 += 32) {
        short8 afh[4], afl[4], bfh[4], bfl[4];
#pragma unroll
        for (int mi = 0; mi < 4; mi++) {
            afh[mi] = *(const short8*)&Akh[(mw + mi * 16 + l16) * 72 + k2 + quad * 8];
            afl[mi] = *(const short8*)&Akl[(mw + mi * 16 + l16) * 72 + k2 + quad * 8];
        }
#pragma unroll
        for (int ni = 0; ni < 4; ni++) {
            bfh[ni] = *(const short8*)&Bqh[(nw + ni * 16 + l16) * 72 + k2 + quad * 8];
            bfl[ni] = *(const short8*)&Bql[(nw + ni * 16 + l16) * 72 + k2 + quad * 8];
        }
#pragma unroll
        for (int mi = 0; mi < 4; mi++)
#pragma unroll
            for (int ni = 0; ni < 4; ni++) {
                MFMA(acc[mi][ni], afh[mi], bfh[ni]);
                MFMA(acc[mi][ni], afh[mi], bfl[ni]);
                MFMA(acc[mi][ni], afl[mi], bfh[ni]);
            }
    }
    __syncthreads();  // staging reads done; reuse smem for e

    // el[h][g], diag -inf
#pragma unroll
    for (int mi = 0; mi < 4; mi++) {
        int g0 = mw + mi * 16 + quad * 4;
#pragma unroll
        for (int ni = 0; ni < 4; ni++) {
            int h_ = nw + ni * 16 + l16;
            f32x4 vv = acc[mi][ni];
#pragma unroll
            for (int r = 0; r < 4; r++)
                if (g0 + r == h_) vv[r] = -INFINITY;
            *(f32x4*)&el[h_ * 132 + g0] = vv;
        }
    }
    __syncthreads();

    int h2 = t >> 1, half = t & 1;
    const float* ewr = ew + (((size_t)(b * Wn + w)) * Hn + h2) * Wn + half * 64;
    const float* ehr = &el[h2 * 132 + half * 64];
    f32x4 ew4[16], eh4[16];
#pragma unroll
    for (int i = 0; i < 16; i++) ew4[i] = *(const f32x4*)&ewr[i * 4];
#pragma unroll
    for (int i = 0; i < 16; i++) eh4[i] = *(const f32x4*)&ehr[i * 4];

    float mx = -INFINITY;
#pragma unroll
    for (int i = 0; i < 16; i++)
#pragma unroll
        for (int r = 0; r < 4; r++) {
            mx = fmaxf(mx, eh4[i][r]);
            mx = fmaxf(mx, ew4[i][r]);
        }
    mx = fmaxf(mx, __shfl_xor(mx, 1, 64));

    float s = 0.f;
#pragma unroll
    for (int i = 0; i < 16; i++)
#pragma unroll
        for (int r = 0; r < 4; r++) {
            float e1 = __expf(eh4[i][r] - mx); eh4[i][r] = e1; s += e1;
            float e2 = __expf(ew4[i][r] - mx); ew4[i][r] = e2; s += e2;
        }
    s += __shfl_xor(s, 1, 64);
    float inv = 1.f / s;

    u16* aHr = aH + (((size_t)(b * Wn + w)) * Hn + h2) * Hn + half * 64;
    u16* aWr = aW + (((size_t)(b * Hn + h2)) * Wn + w) * Wn + half * 64;
#pragma unroll
    for (int i = 0; i < 16; i++) {
        uint2 p, q2;
        p.x  = (u32)f2b(eh4[i][0] * inv) | ((u32)f2b(eh4[i][1] * inv) << 16);
        p.y  = (u32)f2b(eh4[i][2] * inv) | ((u32)f2b(eh4[i][3] * inv) << 16);
        q2.x = (u32)f2b(ew4[i][0] * inv) | ((u32)f2b(ew4[i][1] * inv) << 16);
        q2.y = (u32)f2b(ew4[i][2] * inv) | ((u32)f2b(ew4[i][3] * inv) << 16);
        *(uint2*)&aHr[i * 4] = p;
        *(uint2*)&aWr[i * 4] = q2;
    }
}

// ---------------------------------------------------------------- K3b
// per (b,w,ct): D[c,h] = sum_g v_t[b,w,g,c] * aH[b,w,h,g] -> oh (B,W,H,C)
__global__ __launch_bounds__(256) void k3b_outh(
    const u16* __restrict__ vt, const u16* __restrict__ aH, u16* __restrict__ oh)
{
    __shared__ u16 Al[128 * 136];  // [c][g], g XOR-swizzled by ((c>>3)&15)<<3
    __shared__ u16 Bl[128 * 136];  // [h][g]
    int bid = blockIdx.x;
    int ct = bid & 3, w = (bid >> 2) & 127, b = bid >> 9;
    int t = threadIdx.x;
    int lane = t & 63, wid = t >> 6;
    int quad = lane >> 4, l16 = lane & 15;
    int mw = (wid >> 1) * 64, nw = (wid & 1) * 64;

    const u16* vtb = vt + ((size_t)(b * Wn + w)) * Hn * Cn;  // [g][c]
    const u16* aHb = aH + ((size_t)(b * Wn + w)) * Hn * Hn;  // [h][g]
#pragma unroll
    for (int i = 0; i < 8; i++) {
        int chunk = i * 256 + t;              // 2048 chunks of 8
        int g = chunk >> 4, c8 = (chunk & 15) << 3;
        short8 d = *(const short8*)(vtb + (size_t)g * Cn + ct * 128 + c8);
        u16* dp = (u16*)&d;
        int gs = g ^ ((chunk & 15) << 3);     // ((c8+j)>>3)&15 == chunk&15
#pragma unroll
        for (int j = 0; j < 8; j++) Al[(c8 + j) * 136 + gs] = dp[j];
    }
#pragma unroll
    for (int i = 0; i < 8; i++) {
        int chunk = i * 256 + t;
        int h_ = chunk >> 4, g8 = (chunk & 15) << 3;
        *(short8*)&Bl[h_ * 136 + g8] = *(const short8*)(aHb + (size_t)h_ * Hn + g8);
    }
    __syncthreads();

    f32x4 acc[4][4];
#pragma unroll
    for (int i = 0; i < 4; i++)
#pragma unroll
        for (int j = 0; j < 4; j++) acc[i][j] = (f32x4){0.f, 0.f, 0.f, 0.f};
#pragma unroll
    for (int kk = 0; kk < 128; kk += 32) {
        short8 af[4], bf[4];
#pragma unroll
        for (int mi = 0; mi < 4; mi++) {
            int row = mw + mi * 16 + l16;
            int col = (kk + quad * 8) ^ (((row >> 3) & 15) << 3);
            af[mi] = *(const short8*)&Al[row * 136 + col];
        }
#pragma unroll
        for (int ni = 0; ni < 4; ni++)
            bf[ni] = *(const short8*)&Bl[(nw + ni * 16 + l16) * 136 + kk + quad * 8];
#pragma unroll
        for (int mi = 0; mi < 4; mi++)
#pragma unroll
            for (int ni = 0; ni < 4; ni++) MFMA(acc[mi][ni], af[mi], bf[ni]);
    }

#pragma unroll
    for (int mi = 0; mi < 4; mi++) {
        int c0 = mw + mi * 16 + quad * 4;
#pragma unroll
        for (int ni = 0; ni < 4; ni++) {
            int h_ = nw + ni * 16 + l16;
            u16 o[4];
#pragma unroll
            for (int r = 0; r < 4; r++) o[r] = f2b(acc[mi][ni][r]);
            uint2 p;
            p.x = (u32)o[0] | ((u32)o[1] << 16);
            p.y = (u32)o[2] | ((u32)o[3] << 16);
            *(uint2*)(oh + ((size_t)(b * Wn + w) * Hn + h_) * Cn + ct * 128 + c0) = p;
        }
    }
}

// ---------------------------------------------------------------- K4
// per (b,h,ct): D[c,w] = sum_v v_t[b,v,h,c] * aW[b,h,w,v];
// out = GAMMA*(D + oh) + x   (fp32 x, fp32 out)
__global__ __launch_bounds__(256) void k4_final(
    const u16* __restrict__ vt, const u16* __restrict__ aW,
    const u16* __restrict__ oh, const float* __restrict__ x, float* __restrict__ out)
{
    __shared__ u16 Al[128 * 136];  // [c][v], v XOR-swizzled by ((c>>3)&15)<<3
    __shared__ u16 Bl[128 * 136];  // [w][v]
    int bid = blockIdx.x;
    int ct = bid & 3, h = (bid >> 2) & 127, b = bid >> 9;
    int t = threadIdx.x;
    int lane = t & 63, wid = t >> 6;
    int quad = lane >> 4, l16 = lane & 15;
    int mw = (wid >> 1) * 64, nw = (wid & 1) * 64;

    const u16* aWb = aW + ((size_t)(b * Hn + h)) * Wn * Wn;  // [w][v]
#pragma unroll
    for (int i = 0; i < 8; i++) {
        int chunk = i * 256 + t;
        int vv = chunk >> 4, c8 = (chunk & 15) << 3;
        short8 d = *(const short8*)(vt + ((size_t)(b * Wn + vv) * Hn + h) * Cn + ct * 128 + c8);
        u16* dp = (u16*)&d;
        int vs = vv ^ ((chunk & 15) << 3);
#pragma unroll
        for (int j = 0; j < 8; j++) Al[(c8 + j) * 136 + vs] = dp[j];
    }
#pragma unroll
    for (int i = 0; i < 8; i++) {
        int chunk = i * 256 + t;
        int w_ = chunk >> 4, v8 = (chunk & 15) << 3;
        *(short8*)&Bl[w_ * 136 + v8] = *(const short8*)(aWb + (size_t)w_ * Wn + v8);
    }
    __syncthreads();

    f32x4 acc[4][4];
#pragma unroll
    for (int i = 0; i < 4; i++)
#pragma unroll
        for (int j = 0; j < 4; j++) acc[i][j] = (f32x4){0.f, 0.f, 0.f, 0.f};
#pragma unroll
    for (int kk = 0; kk < 128; kk += 32) {
        short8 af[4], bf[4];
#pragma unroll
        for (int mi = 0; mi < 4; mi++) {
            int row = mw + mi * 16 + l16;
            int col = (kk + quad * 8) ^ (((row >> 3) & 15) << 3);
            af[mi] = *(const short8*)&Al[row * 136 + col];
        }
#pragma unroll
        for (int ni = 0; ni < 4; ni++)
            bf[ni] = *(const short8*)&Bl[(nw + ni * 16 + l16) * 136 + kk + quad * 8];
#pragma unroll
        for (int mi = 0; mi < 4; mi++)
#pragma unroll
            for (int ni = 0; ni < 4; ni++) MFMA(acc[mi][ni], af[mi], bf[ni]);
    }

#pragma unroll
    for (int mi = 0; mi < 4; mi++) {
        int c0 = mw + mi * 16 + quad * 4;
        int cg = ct * 128 + c0;
#pragma unroll
        for (int ni = 0; ni < 4; ni++) {
            int w_ = nw + ni * 16 + l16;
            uint2 ohp = *(const uint2*)(oh + ((size_t)(b * Wn + w_) * Hn + h) * Cn + cg);
            u16* ohs = (u16*)&ohp;
#pragma unroll
            for (int r = 0; r < 4; r++) {
                size_t xi = (((size_t)(b * Cn + cg + r)) * Hn + h) * Wn + w_;
                out[xi] = GAMMA_F * (acc[mi][ni][r] + b2f(ohs[r])) + x[xi];
            }
        }
    }
}

// ---------------------------------------------------------------- launch
extern "C" void kernel_launch(void* const* d_in, const int* in_sizes, int n_in,
                              void* d_out, int out_size, void* d_ws, size_t ws_size,
                              hipStream_t stream) {
    const float* x  = (const float*)d_in[0];
    const float* wq = (const float*)d_in[1];
    const float* bq = (const float*)d_in[2];
    const float* wk = (const float*)d_in[3];
    const float* bk = (const float*)d_in[4];
    const float* wv = (const float*)d_in[5];
    const float* bv = (const float*)d_in[6];
    float* out = (float*)d_out;
    char* ws = (char*)d_ws;

    // workspace layout (lifetime-overlapped), total 335,544,320 B:
    //  vt:  [0, 134217728)                 (B,W,H,C) bf16
    //  qh:  [134217728, 150994944)         (B,H,W,CQ) bf16
    //  ql:  [150994944, 167772160)
    //  kh:  [167772160, 184549376)
    //  kl:  [184549376, 201326592)
    //  ew:  [201326592, 268435456)         (B,W,H,W) fp32
    //  wqkh/wqkl/wvt: head of ew region (786432 B) — consumed before K2 writes ew
    //  aH:  [268435456, 301989888)         (B,W,H,H) bf16
    //  aW:  [301989888, 335544320)         (B,H,W,W) bf16
    //  oh:  [134217728, 268435456)         (B,W,H,C) bf16 — overlaps qh..ew, dead by K3b
    // d_out doubles as scratch before K4 overwrites it:
    //  xh:  d_out[0, 134217728)            (B,H,W,C) bf16 — hi split of x, transposed;
    //       written by K1qk, read by K1v, dead before K4 writes out.
    u16*  vt   = (u16*)(ws + 0);
    u16*  qh   = (u16*)(ws + 134217728);
    u16*  ql   = (u16*)(ws + 150994944);
    u16*  kh   = (u16*)(ws + 167772160);
    u16*  kl   = (u16*)(ws + 184549376);
    float* ew  = (float*)(ws + 201326592);
    u16*  wqkh = (u16*)(ws + 201326592);
    u16*  wqkl = (u16*)(ws + 201326592 + 131072);
    u16*  wvt  = (u16*)(ws + 201326592 + 262144);
    u16*  aH   = (u16*)(ws + 268435456);
    u16*  aW   = (u16*)(ws + 301989888);
    u16*  oh   = (u16*)(ws + 134217728);
    u16*  xh   = (u16*)d_out;

    k0_wt<<<dim3(1280), dim3(256), 0, stream>>>(wq, wk, wv, wqkh, wqkl, wvt);
    k1_qk<<<dim3(Bn * 128), dim3(256), 0, stream>>>(x, wqkh, wqkl, bq, bk, qh, ql, kh, kl, xh);
    k1_v<<<dim3(Bn * 512), dim3(256), 0, stream>>>(xh, wvt, bv, vt);
    k2_ew<<<dim3(Bn * Hn), dim3(256), 0, stream>>>(qh, ql, kh, kl, ew);
    k3a_soft<<<dim3(Bn * Wn), dim3(256), 0, stream>>>(qh, ql, kh, kl, ew, aH, aW);
    k3b_outh<<<dim3(Bn * Wn * 4), dim3(256), 0, stream>>>(vt, aH, oh);
    k4_final<<<dim3(Bn * Hn * 4), dim3(256), 0, stream>>>(vt, aW, oh, x, out);
}

// Round 2
// 898.307 us; speedup vs baseline: 1.2982x; 1.0246x over previous
//
#include <hip/hip_runtime.h>

// CrissCrossAttention on MI355X (gfx950). fp32 I/O.
// q/k path in split-bf16 (hi+lo, 3-MFMA products) for fp32-grade energies;
// v path in plain bf16. B=8, C=512, CQ=64, H=W=128.
//
//  K0:  weights -> wqk hi/lo bf16 [m][c] (m<128), wv bf16 [m][c] (m<512)
//  K1qk: q,k projection, split-bf16 x and W -> qh,ql,kh,kl (B,H,W,CQ) bf16
//        + writes xh (B,H,W,C) bf16 (hi split of x, transposed) into d_out scratch
//  K1v:  v projection from xh (pure bf16 GEMM, no transpose/convert) -> vt (B,W,H,C)
//  K2:  e_W[b,h,w,v] = q.k (split, 3 MFMAs) -> ew (B,W,H,W) fp32
//  K3a: per (b,w): e_H (split MFMA) + ew slice -> joint softmax ->
//       aH (B,W,H,H) bf16, aW (B,H,W,W) bf16
//  K3b: out_H -> oh (B,W,H,C) bf16  [LDS-transposed epilogue: coalesced short8]
//  K4:  out_W + GAMMA*(oh+ow) + x -> out (B,C,H,W) fp32
//       [LDS-transposed epilogue: oh staged via LDS, float4 x/out, coalesced]
//
// This round: k4/k3b epilogues were issue/latency-bound (144 scalar VMEM ops
// per thread in k4, 128KB-strided uint2 oh loads). Replaced with LDS-transpose
// epilogues: all global traffic is now >=256B-segment coalesced.

#define Bn 8
#define Cn 512
#define CQn 64
#define Hn 128
#define Wn 128
#define HWn (Hn*Wn)
#define GAMMA_F 1.0f

typedef __attribute__((ext_vector_type(8))) short short8;
typedef __attribute__((ext_vector_type(4))) float f32x4;
typedef unsigned short u16;
typedef unsigned int u32;

__device__ __forceinline__ float b2f(u16 h) {
    union { u32 u; float f; } v; v.u = ((u32)h) << 16; return v.f;
}
__device__ __forceinline__ u16 f2b(float f) {
    union { float f; u32 u; } v; v.f = f;
    u32 u = v.u;
    return (u16)((u + 0x7fffu + ((u >> 16) & 1u)) >> 16);  // RNE
}

#define MFMA(acc, a, b) acc = __builtin_amdgcn_mfma_f32_16x16x32_bf16(a, b, acc, 0, 0, 0)

// ---------------------------------------------------------------- K0
__global__ __launch_bounds__(256) void k0_wt(const float* __restrict__ wq,
                                             const float* __restrict__ wk,
                                             const float* __restrict__ wv,
                                             u16* __restrict__ wqkh, u16* __restrict__ wqkl,
                                             u16* __restrict__ wvt) {
    int idx = blockIdx.x * 256 + threadIdx.x;  // 128*512 + 512*512
    if (idx >= 128 * 512 + 512 * 512) return;
    if (idx < 128 * 512) {
        int m = idx >> 9, c = idx & 511;
        float v = (m < 64) ? wq[c * 64 + m] : wk[c * 64 + (m - 64)];
        u16 hi = f2b(v);
        wqkh[idx] = hi;
        wqkl[idx] = f2b(v - b2f(hi));
    } else {
        int j = idx - 128 * 512;
        int m = j >> 9, c = j & 511;
        wvt[j] = f2b(wv[c * 512 + m]);
    }
}

// ---------------------------------------------------------------- K1qk
// per (b,h): D[m,w] = sum_c Wqk[m,c] x[b,c,h,w], m in [0,128) = [q|k]
// split-bf16 both operands: acc = Ah*Bh + Ah*Bl + Al*Bh
// Also writes the staged hi-tile of x out to xh (B,H,W,C) for k1_v.
__global__ __launch_bounds__(256) void k1_qk(
    const float* __restrict__ x, const u16* __restrict__ wqkh, const u16* __restrict__ wqkl,
    const float* __restrict__ bq, const float* __restrict__ bk,
    u16* __restrict__ qh, u16* __restrict__ ql, u16* __restrict__ kh, u16* __restrict__ kl,
    u16* __restrict__ xh)
{
    __shared__ u16 Ahi[128 * 72];
    __shared__ u16 Alo[128 * 72];
    __shared__ u16 Bhi[128 * 72];
    __shared__ u16 Blo[128 * 72];
    int bid = blockIdx.x;
    int b = bid >> 7, h = bid & 127;
    int t = threadIdx.x;
    int lane = t & 63, wid = t >> 6;
    int quad = lane >> 4, l16 = lane & 15;
    int mw = (wid >> 1) * 64, nw = (wid & 1) * 64;

    f32x4 acc[4][4];
#pragma unroll
    for (int i = 0; i < 4; i++)
#pragma unroll
        for (int j = 0; j < 4; j++) acc[i][j] = (f32x4){0.f, 0.f, 0.f, 0.f};

    const float* xb = x + (size_t)b * Cn * HWn + (size_t)h * 128;
    u16* xhb = xh + ((size_t)(b * Hn + h)) * Wn * Cn;

    for (int ks = 0; ks < 8; ks++) {
        int c0 = ks * 64;
#pragma unroll
        for (int i = 0; i < 4; i++) {
            int chunk = i * 256 + t;            // 1024 chunks of 8
            int m = chunk >> 3, kq = chunk & 7;
            *(short8*)&Ahi[m * 72 + kq * 8] = *(const short8*)(wqkh + (size_t)m * 512 + c0 + kq * 8);
            *(short8*)&Alo[m * 72 + kq * 8] = *(const short8*)(wqkl + (size_t)m * 512 + c0 + kq * 8);
        }
#pragma unroll
        for (int i = 0; i < 4; i++) {
            int chunk = i * 256 + t;
            int kk = chunk >> 4, m = chunk & 15, n8 = m << 3;
            const float* src = xb + (size_t)(c0 + kk) * HWn + n8;
            float4 d0 = *(const float4*)(src);
            float4 d1 = *(const float4*)(src + 4);
            float f[8] = {d0.x, d0.y, d0.z, d0.w, d1.x, d1.y, d1.z, d1.w};
            int col = kk ^ ((m & 7) << 3);      // XOR-swizzle: kills 16-way write conflict
#pragma unroll
            for (int j = 0; j < 8; j++) {
                u16 hi = f2b(f[j]);
                Bhi[(n8 + j) * 72 + col] = hi;
                Blo[(n8 + j) * 72 + col] = f2b(f[j] - b2f(hi));
            }
        }
        __syncthreads();
#pragma unroll
        for (int k2 = 0; k2 < 64; k2 += 32) {
            short8 afh[4], afl[4], bfh[4], bfl[4];
#pragma unroll
            for (int mi = 0; mi < 4; mi++) {
                afh[mi] = *(const short8*)&Ahi[(mw + mi * 16 + l16) * 72 + k2 + quad * 8];
                afl[mi] = *(const short8*)&Alo[(mw + mi * 16 + l16) * 72 + k2 + quad * 8];
            }
#pragma unroll
            for (int ni = 0; ni < 4; ni++) {
                int wrow = nw + ni * 16 + l16;
                int col = (k2 + quad * 8) ^ (((wrow >> 3) & 7) << 3);
                bfh[ni] = *(const short8*)&Bhi[wrow * 72 + col];
                bfl[ni] = *(const short8*)&Blo[wrow * 72 + col];
            }
#pragma unroll
            for (int mi = 0; mi < 4; mi++)
#pragma unroll
                for (int ni = 0; ni < 4; ni++) {
                    MFMA(acc[mi][ni], afh[mi], bfh[ni]);
                    MFMA(acc[mi][ni], afh[mi], bfl[ni]);
                    MFMA(acc[mi][ni], afl[mi], bfh[ni]);
                }
        }
        // write staged hi-tile of x out (transposed, de-swizzled) -> xh[b][h][w][c]
#pragma unroll
        for (int p = 0; p < 4; p++) {
            int w = p * 32 + (t >> 3), kq = t & 7;
            int col = (kq * 8) ^ (((w >> 3) & 7) << 3);
            *(short8*)(xhb + (size_t)w * Cn + c0 + kq * 8) = *(const short8*)&Bhi[w * 72 + col];
        }
        __syncthreads();
    }

#pragma unroll
    for (int mi = 0; mi < 4; mi++) {
        int gm = mw + mi * 16 + quad * 4;   // 0..124, 4 consecutive channels
        float bias[4];
#pragma unroll
        for (int r = 0; r < 4; r++) {
            int g = gm + r;
            bias[r] = (g < 64) ? bq[g] : bk[g - 64];
        }
#pragma unroll
        for (int ni = 0; ni < 4; ni++) {
            int w = nw + ni * 16 + l16;
            u16 oh_[4], ol_[4];
#pragma unroll
            for (int r = 0; r < 4; r++) {
                float val = acc[mi][ni][r] + bias[r];
                oh_[r] = f2b(val);
                ol_[r] = f2b(val - b2f(oh_[r]));
            }
            uint2 ph, pl;
            ph.x = (u32)oh_[0] | ((u32)oh_[1] << 16);
            ph.y = (u32)oh_[2] | ((u32)oh_[3] << 16);
            pl.x = (u32)ol_[0] | ((u32)ol_[1] << 16);
            pl.y = (u32)ol_[2] | ((u32)ol_[3] << 16);
            size_t base = ((size_t)((b * Hn + h) * Wn + w)) * CQn;
            if (gm < 64) {
                *(uint2*)(qh + base + gm) = ph;
                *(uint2*)(ql + base + gm) = pl;
            } else {
                *(uint2*)(kh + base + gm - 64) = ph;
                *(uint2*)(kl + base + gm - 64) = pl;
            }
        }
    }
}

// ---------------------------------------------------------------- K1v
// per (b,mt,h): D[m,w] = sum_c Wv[m,c] xh[b,h,w,c] -> vt (B,W,H,C) bf16
__global__ __launch_bounds__(256) void k1_v(
    const u16* __restrict__ xh, const u16* __restrict__ wvt,
    const float* __restrict__ bv, u16* __restrict__ vt)
{
    __shared__ u16 Al[128 * 72];
    __shared__ u16 Bl[128 * 72];
    int bid = blockIdx.x;
    int b = bid / 512;
    int rem = bid % 512;
    int mt = rem >> 7, h = rem & 127;
    int t = threadIdx.x;
    int lane = t & 63, wid = t >> 6;
    int quad = lane >> 4, l16 = lane & 15;
    int mw = (wid >> 1) * 64, nw = (wid & 1) * 64;

    f32x4 acc[4][4];
#pragma unroll
    for (int i = 0; i < 4; i++)
#pragma unroll
        for (int j = 0; j < 4; j++) acc[i][j] = (f32x4){0.f, 0.f, 0.f, 0.f};

    const u16* xhb = xh + ((size_t)(b * Hn + h)) * Wn * Cn;
    const u16* wtm = wvt + (size_t)(mt * 128) * 512;

    for (int ks = 0; ks < 8; ks++) {
        int c0 = ks * 64;
#pragma unroll
        for (int i = 0; i < 4; i++) {
            int chunk = i * 256 + t;
            int m = chunk >> 3, kq = chunk & 7;
            *(short8*)&Al[m * 72 + kq * 8] = *(const short8*)(wtm + (size_t)m * 512 + c0 + kq * 8);
        }
#pragma unroll
        for (int i = 0; i < 4; i++) {
            int chunk = i * 256 + t;
            int w = chunk >> 3, kq = chunk & 7;
            *(short8*)&Bl[w * 72 + kq * 8] = *(const short8*)(xhb + (size_t)w * Cn + c0 + kq * 8);
        }
        __syncthreads();
#pragma unroll
        for (int k2 = 0; k2 < 64; k2 += 32) {
            short8 af[4], bf[4];
#pragma unroll
            for (int mi = 0; mi < 4; mi++)
                af[mi] = *(const short8*)&Al[(mw + mi * 16 + l16) * 72 + k2 + quad * 8];
#pragma unroll
            for (int ni = 0; ni < 4; ni++)
                bf[ni] = *(const short8*)&Bl[(nw + ni * 16 + l16) * 72 + k2 + quad * 8];
#pragma unroll
            for (int mi = 0; mi < 4; mi++)
#pragma unroll
                for (int ni = 0; ni < 4; ni++) MFMA(acc[mi][ni], af[mi], bf[ni]);
        }
        __syncthreads();
    }

#pragma unroll
    for (int mi = 0; mi < 4; mi++) {
        int gm = mt * 128 + mw + mi * 16 + quad * 4;
        float bias[4];
#pragma unroll
        for (int r = 0; r < 4; r++) bias[r] = bv[gm + r];
#pragma unroll
        for (int ni = 0; ni < 4; ni++) {
            int w = nw + ni * 16 + l16;
            u16 o[4];
#pragma unroll
            for (int r = 0; r < 4; r++) o[r] = f2b(acc[mi][ni][r] + bias[r]);
            uint2 p;
            p.x = (u32)o[0] | ((u32)o[1] << 16);
            p.y = (u32)o[2] | ((u32)o[3] << 16);
            *(uint2*)(vt + ((size_t)((b * Wn + w) * Hn + h)) * Cn + gm) = p;
        }
    }
}

// ---------------------------------------------------------------- K2
// D[v,w] = sum_d k_row[v,d] * q_row[w,d] (split) -> ew[((b*W+w)*H+h)*W + v]
__global__ __launch_bounds__(256) void k2_ew(
    const u16* __restrict__ qh, const u16* __restrict__ ql,
    const u16* __restrict__ kh, const u16* __restrict__ kl, float* __restrict__ ew)
{
    __shared__ u16 Akh[128 * 72];
    __shared__ u16 Akl[128 * 72];
    __shared__ u16 Bqh[128 * 72];
    __shared__ u16 Bql[128 * 72];
    int bid = blockIdx.x;
    int b = bid >> 7, h = bid & 127;
    int t = threadIdx.x;
    int lane = t & 63, wid = t >> 6;
    int quad = lane >> 4, l16 = lane & 15;
    int mw = (wid >> 1) * 64, nw = (wid & 1) * 64;

    size_t rowbase = ((size_t)(b * Hn + h)) * Wn * CQn;
#pragma unroll
    for (int i = 0; i < 4; i++) {
        int chunk = i * 256 + t;
        int row = chunk >> 3, kq = chunk & 7;
        size_t off = rowbase + row * 64 + kq * 8;
        *(short8*)&Akh[row * 72 + kq * 8] = *(const short8*)&kh[off];
        *(short8*)&Akl[row * 72 + kq * 8] = *(const short8*)&kl[off];
        *(short8*)&Bqh[row * 72 + kq * 8] = *(const short8*)&qh[off];
        *(short8*)&Bql[row * 72 + kq * 8] = *(const short8*)&ql[off];
    }
    __syncthreads();

    f32x4 acc[4][4];
#pragma unroll
    for (int i = 0; i < 4; i++)
#pragma unroll
        for (int j = 0; j < 4; j++) acc[i][j] = (f32x4){0.f, 0.f, 0.f, 0.f};
#pragma unroll
    for (int k2 = 0; k2 < 64; k2 += 32) {
        short8 afh[4], afl[4], bfh[4], bfl[4];
#pragma unroll
        for (int mi = 0; mi < 4; mi++) {
            afh[mi] = *(const short8*)&Akh[(mw + mi * 16 + l16) * 72 + k2 + quad * 8];
            afl[mi] = *(const short8*)&Akl[(mw + mi * 16 + l16) * 72 + k2 + quad * 8];
        }
#pragma unroll
        for (int ni = 0; ni < 4; ni++) {
            bfh[ni] = *(const short8*)&Bqh[(nw + ni * 16 + l16) * 72 + k2 + quad * 8];
            bfl[ni] = *(const short8*)&Bql[(nw + ni * 16 + l16) * 72 + k2 + quad * 8];
        }
#pragma unroll
        for (int mi = 0; mi < 4; mi++)
#pragma unroll
            for (int ni = 0; ni < 4; ni++) {
                MFMA(acc[mi][ni], afh[mi], bfh[ni]);
                MFMA(acc[mi][ni], afh[mi], bfl[ni]);
                MFMA(acc[mi][ni], afl[mi], bfh[ni]);
            }
    }
#pragma unroll
    for (int mi = 0; mi < 4; mi++) {
        int v0 = mw + mi * 16 + quad * 4;
#pragma unroll
        for (int ni = 0; ni < 4; ni++) {
            int w = nw + ni * 16 + l16;
            *(f32x4*)(ew + ((size_t)((b * Wn + w) * Hn + h)) * Wn + v0) = acc[mi][ni];
        }
    }
}

// ---------------------------------------------------------------- K3a
// per (b,w): e_H[g,h] split MFMA, diag mask, joint softmax with ew slice
__global__ __launch_bounds__(256) void k3a_soft(
    const u16* __restrict__ qh, const u16* __restrict__ ql,
    const u16* __restrict__ kh, const u16* __restrict__ kl,
    const float* __restrict__ ew, u16* __restrict__ aH, u16* __restrict__ aW)
{
    __shared__ char smem[73728];             // 4 staging tiles, then e[h][132] fp32
    u16* Akh = (u16*)smem;
    u16* Akl = (u16*)(smem + 18432);
    u16* Bqh = (u16*)(smem + 36864);
    u16* Bql = (u16*)(smem + 55296);
    float* el = (float*)smem;

    int bid = blockIdx.x;
    int b = bid >> 7, w = bid & 127;
    int t = threadIdx.x;
    int lane = t & 63, wid = t >> 6;
    int quad = lane >> 4, l16 = lane & 15;
    int mw = (wid >> 1) * 64, nw = (wid & 1) * 64;

#pragma unroll
    for (int i = 0; i < 4; i++) {
        int chunk = i * 256 + t;
        int row = chunk >> 3, kq = chunk & 7;
        size_t off = ((size_t)((b * Hn + row) * Wn + w)) * CQn + kq * 8;
        *(short8*)&Akh[row * 72 + kq * 8] = *(const short8*)&kh[off];
        *(short8*)&Akl[row * 72 + kq * 8] = *(const short8*)&kl[off];
        *(short8*)&Bqh[row * 72 + kq * 8] = *(const short8*)&qh[off];
        *(short8*)&Bql[row * 72 + kq * 8] = *(const short8*)&ql[off];
    }
    __syncthreads();

    f32x4 acc[4][4];
#pragma unroll
    for (int i = 0; i < 4; i++)
#pragma unroll
        for (int j = 0; j < 4; j++) acc[i][j] = (f32x4){0.f, 0.f, 0.f, 0.f};
#pragma unroll
    for (int k2 = 0; k2 < 64; k2 += 32) {
        short8 afh[4], afl[4], bfh[4], bfl[4];
#pragma unroll
        for (int mi = 0; mi < 4; mi++) {
            afh[mi] = *(const short8*)&Akh[(mw + mi * 16 + l16) * 72 + k2 + quad * 8];
            afl[mi] = *(const short8*)&Akl[(mw + mi * 16 + l16) * 72 + k2 + quad * 8];
        }
#pragma unroll
        for (int ni = 0; ni < 4; ni++) {
            bfh[ni] = *(const short8*)&Bqh[(nw + ni * 16 + l16) * 72 + k2 + quad * 8];
            bfl[ni] = *(const short8*)&Bql[(nw + ni * 16 + l16) * 72 + k2 + quad * 8];
        }
#pragma unroll
        for (int mi = 0; mi < 4; mi++)
#pragma unroll
            for (int ni = 0; ni < 4; ni++) {
                MFMA(acc[mi][ni], afh[mi], bfh[ni]);
                MFMA(acc[mi][ni], afh[mi], bfl[ni]);
                MFMA(acc[mi][ni], afl[mi], bfh[ni]);
            }
    }
    __syncthreads();  // staging reads done; reuse smem for e

    // el[h][g], diag -inf
#pragma unroll
    for (int mi = 0; mi < 4; mi++) {
        int g0 = mw + mi * 16 + quad * 4;
#pragma unroll
        for (int ni = 0; ni < 4; ni++) {
            int h_ = nw + ni * 16 + l16;
            f32x4 vv = acc[mi][ni];
#pragma unroll
            for (int r = 0; r < 4; r++)
                if (g0 + r == h_) vv[r] = -INFINITY;
            *(f32x4*)&el[h_ * 132 + g0] = vv;
        }
    }
    __syncthreads();

    int h2 = t >> 1, half = t & 1;
    const float* ewr = ew + (((size_t)(b * Wn + w)) * Hn + h2) * Wn + half * 64;
    const float* ehr = &el[h2 * 132 + half * 64];
    f32x4 ew4[16], eh4[16];
#pragma unroll
    for (int i = 0; i < 16; i++) ew4[i] = *(const f32x4*)&ewr[i * 4];
#pragma unroll
    for (int i = 0; i < 16; i++) eh4[i] = *(const f32x4*)&ehr[i * 4];

    float mx = -INFINITY;
#pragma unroll
    for (int i = 0; i < 16; i++)
#pragma unroll
        for (int r = 0; r < 4; r++) {
            mx = fmaxf(mx, eh4[i][r]);
            mx = fmaxf(mx, ew4[i][r]);
        }
    mx = fmaxf(mx, __shfl_xor(mx, 1, 64));

    float s = 0.f;
#pragma unroll
    for (int i = 0; i < 16; i++)
#pragma unroll
        for (int r = 0; r < 4; r++) {
            float e1 = __expf(eh4[i][r] - mx); eh4[i][r] = e1; s += e1;
            float e2 = __expf(ew4[i][r] - mx); ew4[i][r] = e2; s += e2;
        }
    s += __shfl_xor(s, 1, 64);
    float inv = 1.f / s;

    u16* aHr = aH + (((size_t)(b * Wn + w)) * Hn + h2) * Hn + half * 64;
    u16* aWr = aW + (((size_t)(b * Hn + h2)) * Wn + w) * Wn + half * 64;
#pragma unroll
    for (int i = 0; i < 16; i++) {
        uint2 p, q2;
        p.x  = (u32)f2b(eh4[i][0] * inv) | ((u32)f2b(eh4[i][1] * inv) << 16);
        p.y  = (u32)f2b(eh4[i][2] * inv) | ((u32)f2b(eh4[i][3] * inv) << 16);
        q2.x = (u32)f2b(ew4[i][0] * inv) | ((u32)f2b(ew4[i][1] * inv) << 16);
        q2.y = (u32)f2b(ew4[i][2] * inv) | ((u32)f2b(ew4[i][3] * inv) << 16);
        *(uint2*)&aHr[i * 4] = p;
        *(uint2*)&aWr[i * 4] = q2;
    }
}

// ---------------------------------------------------------------- K3b
// per (b,w,ct): D[c,h] = sum_g v_t[b,w,g,c] * aH[b,w,h,g] -> oh (B,W,H,C)
// Epilogue: acc -> LDS bf16 [h][c] tile -> coalesced short8 stores.
__global__ __launch_bounds__(256) void k3b_outh(
    const u16* __restrict__ vt, const u16* __restrict__ aH, u16* __restrict__ oh)
{
    __shared__ u16 Al[128 * 136];  // [c][g], g XOR-swizzled; later: ot [h][c]
    __shared__ u16 Bl[128 * 136];  // [h][g]
    int bid = blockIdx.x;
    int ct = bid & 3, w = (bid >> 2) & 127, b = bid >> 9;
    int t = threadIdx.x;
    int lane = t & 63, wid = t >> 6;
    int quad = lane >> 4, l16 = lane & 15;
    int mw = (wid >> 1) * 64, nw = (wid & 1) * 64;

    const u16* vtb = vt + ((size_t)(b * Wn + w)) * Hn * Cn;  // [g][c]
    const u16* aHb = aH + ((size_t)(b * Wn + w)) * Hn * Hn;  // [h][g]
#pragma unroll
    for (int i = 0; i < 8; i++) {
        int chunk = i * 256 + t;              // 2048 chunks of 8
        int g = chunk >> 4, c8 = (chunk & 15) << 3;
        short8 d = *(const short8*)(vtb + (size_t)g * Cn + ct * 128 + c8);
        u16* dp = (u16*)&d;
        int gs = g ^ ((chunk & 15) << 3);     // ((c8+j)>>3)&15 == chunk&15
#pragma unroll
        for (int j = 0; j < 8; j++) Al[(c8 + j) * 136 + gs] = dp[j];
    }
#pragma unroll
    for (int i = 0; i < 8; i++) {
        int chunk = i * 256 + t;
        int h_ = chunk >> 4, g8 = (chunk & 15) << 3;
        *(short8*)&Bl[h_ * 136 + g8] = *(const short8*)(aHb + (size_t)h_ * Hn + g8);
    }
    __syncthreads();

    f32x4 acc[4][4];
#pragma unroll
    for (int i = 0; i < 4; i++)
#pragma unroll
        for (int j = 0; j < 4; j++) acc[i][j] = (f32x4){0.f, 0.f, 0.f, 0.f};
#pragma unroll
    for (int kk = 0; kk < 128; kk += 32) {
        short8 af[4], bf[4];
#pragma unroll
        for (int mi = 0; mi < 4; mi++) {
            int row = mw + mi * 16 + l16;
            int col = (kk + quad * 8) ^ (((row >> 3) & 15) << 3);
            af[mi] = *(const short8*)&Al[row * 136 + col];
        }
#pragma unroll
        for (int ni = 0; ni < 4; ni++)
            bf[ni] = *(const short8*)&Bl[(nw + ni * 16 + l16) * 136 + kk + quad * 8];
#pragma unroll
        for (int mi = 0; mi < 4; mi++)
#pragma unroll
            for (int ni = 0; ni < 4; ni++) MFMA(acc[mi][ni], af[mi], bf[ni]);
    }
    __syncthreads();  // Al/Bl dead

    // acc -> LDS bf16 [h][c] tile (2-way max conflicts)
    u16* ot = Al;
#pragma unroll
    for (int mi = 0; mi < 4; mi++) {
        int c0 = mw + mi * 16 + quad * 4;
#pragma unroll
        for (int ni = 0; ni < 4; ni++) {
            int h_ = nw + ni * 16 + l16;
            u16 o[4];
#pragma unroll
            for (int r = 0; r < 4; r++) o[r] = f2b(acc[mi][ni][r]);
            uint2 p;
            p.x = (u32)o[0] | ((u32)o[1] << 16);
            p.y = (u32)o[2] | ((u32)o[3] << 16);
            *(uint2*)&ot[h_ * 136 + c0] = p;
        }
    }
    __syncthreads();

    // coalesced short8 stores: 16 lanes cover 256 B contiguous per h
    u16* ohb = oh + ((size_t)(b * Wn + w)) * Hn * Cn + ct * 128;
#pragma unroll
    for (int i = 0; i < 8; i++) {
        int chunk = i * 256 + t;
        int h_ = chunk >> 4, c8 = (chunk & 15) << 3;
        *(short8*)(ohb + (size_t)h_ * Cn + c8) = *(const short8*)&ot[h_ * 136 + c8];
    }
}

// ---------------------------------------------------------------- K4
// per (b,h,ct): D[c,w] = sum_v v_t[b,v,h,c] * aW[b,h,w,v];
// out = GAMMA*(D + oh) + x   (fp32 x, fp32 out)
// Epilogue: oh staged into LDS (XOR-scatter), acc -> fp32 LDS half-tiles,
// final combine with fully-coalesced float4 x-loads / out-stores.
__global__ __launch_bounds__(256) void k4_final(
    const u16* __restrict__ vt, const u16* __restrict__ aW,
    const u16* __restrict__ oh, const float* __restrict__ x, float* __restrict__ out)
{
    __shared__ u16 Al[128 * 136];  // [c][v] swizzled; later: ohT [c][w^s] bf16
    __shared__ u16 Bl[128 * 136];  // [w][v]; later: el fp32 [64][132] half-tile
    int bid = blockIdx.x;
    int ct = bid & 3, h = (bid >> 2) & 127, b = bid >> 9;
    int t = threadIdx.x;
    int lane = t & 63, wid = t >> 6;
    int quad = lane >> 4, l16 = lane & 15;
    int mw = (wid >> 1) * 64, nw = (wid & 1) * 64;

    const u16* aWb = aW + ((size_t)(b * Hn + h)) * Wn * Wn;  // [w][v]
#pragma unroll
    for (int i = 0; i < 8; i++) {
        int chunk = i * 256 + t;
        int vv = chunk >> 4, c8 = (chunk & 15) << 3;
        short8 d = *(const short8*)(vt + ((size_t)(b * Wn + vv) * Hn + h) * Cn + ct * 128 + c8);
        u16* dp = (u16*)&d;
        int vs = vv ^ ((chunk & 15) << 3);
#pragma unroll
        for (int j = 0; j < 8; j++) Al[(c8 + j) * 136 + vs] = dp[j];
    }
#pragma unroll
    for (int i = 0; i < 8; i++) {
        int chunk = i * 256 + t;
        int w_ = chunk >> 4, v8 = (chunk & 15) << 3;
        *(short8*)&Bl[w_ * 136 + v8] = *(const short8*)(aWb + (size_t)w_ * Wn + v8);
    }
    __syncthreads();

    f32x4 acc[4][4];
#pragma unroll
    for (int i = 0; i < 4; i++)
#pragma unroll
        for (int j = 0; j < 4; j++) acc[i][j] = (f32x4){0.f, 0.f, 0.f, 0.f};
#pragma unroll
    for (int kk = 0; kk < 128; kk += 32) {
        short8 af[4], bf[4];
#pragma unroll
        for (int mi = 0; mi < 4; mi++) {
            int row = mw + mi * 16 + l16;
            int col = (kk + quad * 8) ^ (((row >> 3) & 15) << 3);
            af[mi] = *(const short8*)&Al[row * 136 + col];
        }
#pragma unroll
        for (int ni = 0; ni < 4; ni++)
            bf[ni] = *(const short8*)&Bl[(nw + ni * 16 + l16) * 136 + kk + quad * 8];
#pragma unroll
        for (int mi = 0; mi < 4; mi++)
#pragma unroll
            for (int ni = 0; ni < 4; ni++) MFMA(acc[mi][ni], af[mi], bf[ni]);
    }
    __syncthreads();  // Al/Bl staging dead

    // stage oh tile into Al as ohT[c][w ^ ((c>>3 &15)<<3)] (coalesced global reads)
    u16* ohT = Al;
    const u16* ohb = oh + ((size_t)b * Wn) * Hn * Cn + (size_t)h * Cn + ct * 128;
#pragma unroll
    for (int i = 0; i < 8; i++) {
        int chunk = i * 256 + t;
        int w_ = chunk >> 4, c8 = (chunk & 15) << 3;
        short8 d = *(const short8*)(ohb + (size_t)w_ * (Hn * Cn) + c8);
        u16* dp = (u16*)&d;
        int ws = w_ ^ ((chunk & 15) << 3);
#pragma unroll
        for (int j = 0; j < 8; j++) ohT[(c8 + j) * 136 + ws] = dp[j];
    }

    float* el = (float*)Bl;  // [64][132] fp32 half-tile (33792 B <= 34816)

#pragma unroll
    for (int p = 0; p < 2; p++) {
        __syncthreads();     // p=0: ohT staged + Bl dead; p=1: phase-B reads done
        if ((mw >> 6) == p) {
#pragma unroll
            for (int mi = 0; mi < 4; mi++) {
                int c0 = (mw & 63) + mi * 16 + quad * 4;  // local row 0..63
#pragma unroll
                for (int ni = 0; ni < 4; ni++) {
                    int w_ = nw + ni * 16 + l16;
#pragma unroll
                    for (int r = 0; r < 4; r++) el[(c0 + r) * 132 + w_] = acc[mi][ni][r];
                }
            }
        }
        __syncthreads();
        // 64 rows x 128 w: 32 lanes per row, float4 -> fully coalesced
#pragma unroll
        for (int rep = 0; rep < 8; rep++) {
            int crl = rep * 8 + (t >> 5);       // local row in half-tile
            int cr  = p * 64 + crl;             // tile row 0..127
            int w0  = (t & 31) * 4;
            f32x4 ev = *(const f32x4*)&el[crl * 132 + w0];
            int s = ((cr >> 3) & 15) << 3;
            uint2 op = *(const uint2*)&ohT[cr * 136 + (w0 ^ s)];
            u16* ohs = (u16*)&op;
            size_t gx = ((size_t)(b * Cn + ct * 128 + cr)) * HWn + (size_t)h * Wn + w0;
            float4 xv = *(const float4*)(x + gx);
            float4 ov;
            ov.x = GAMMA_F * (ev[0] + b2f(ohs[0])) + xv.x;
            ov.y = GAMMA_F * (ev[1] + b2f(ohs[1])) + xv.y;
            ov.z = GAMMA_F * (ev[2] + b2f(ohs[2])) + xv.z;
            ov.w = GAMMA_F * (ev[3] + b2f(ohs[3])) + xv.w;
            *(float4*)(out + gx) = ov;
        }
    }
}

// ---------------------------------------------------------------- launch
extern "C" void kernel_launch(void* const* d_in, const int* in_sizes, int n_in,
                              void* d_out, int out_size, void* d_ws, size_t ws_size,
                              hipStream_t stream) {
    const float* x  = (const float*)d_in[0];
    const float* wq = (const float*)d_in[1];
    const float* bq = (const float*)d_in[2];
    const float* wk = (const float*)d_in[3];
    const float* bk = (const float*)d_in[4];
    const float* wv = (const float*)d_in[5];
    const float* bv = (const float*)d_in[6];
    float* out = (float*)d_out;
    char* ws = (char*)d_ws;

    // workspace layout (lifetime-overlapped), total 335,544,320 B:
    //  vt:  [0, 134217728)                 (B,W,H,C) bf16
    //  qh:  [134217728, 150994944)         (B,H,W,CQ) bf16
    //  ql:  [150994944, 167772160)
    //  kh:  [167772160, 184549376)
    //  kl:  [184549376, 201326592)
    //  ew:  [201326592, 268435456)         (B,W,H,W) fp32
    //  wqkh/wqkl/wvt: head of ew region (786432 B) — consumed before K2 writes ew
    //  aH:  [268435456, 301989888)         (B,W,H,H) bf16
    //  aW:  [301989888, 335544320)         (B,H,W,W) bf16
    //  oh:  [134217728, 268435456)         (B,W,H,C) bf16 — overlaps qh..ew, dead by K3b
    // d_out doubles as scratch before K4 overwrites it:
    //  xh:  d_out[0, 134217728)            (B,H,W,C) bf16 — hi split of x, transposed;
    //       written by K1qk, read by K1v, dead before K4 writes out.
    u16*  vt   = (u16*)(ws + 0);
    u16*  qh   = (u16*)(ws + 134217728);
    u16*  ql   = (u16*)(ws + 150994944);
    u16*  kh   = (u16*)(ws + 167772160);
    u16*  kl   = (u16*)(ws + 184549376);
    float* ew  = (float*)(ws + 201326592);
    u16*  wqkh = (u16*)(ws + 201326592);
    u16*  wqkl = (u16*)(ws + 201326592 + 131072);
    u16*  wvt  = (u16*)(ws + 201326592 + 262144);
    u16*  aH   = (u16*)(ws + 268435456);
    u16*  aW   = (u16*)(ws + 301989888);
    u16*  oh   = (u16*)(ws + 134217728);
    u16*  xh   = (u16*)d_out;

    k0_wt<<<dim3(1280), dim3(256), 0, stream>>>(wq, wk, wv, wqkh, wqkl, wvt);
    k1_qk<<<dim3(Bn * 128), dim3(256), 0, stream>>>(x, wqkh, wqkl, bq, bk, qh, ql, kh, kl, xh);
    k1_v<<<dim3(Bn * 512), dim3(256), 0, stream>>>(xh, wvt, bv, vt);
    k2_ew<<<dim3(Bn * Hn), dim3(256), 0, stream>>>(qh, ql, kh, kl, ew);
    k3a_soft<<<dim3(Bn * Wn), dim3(256), 0, stream>>>(qh, ql, kh, kl, ew, aH, aW);
    k3b_outh<<<dim3(Bn * Wn * 4), dim3(256), 0, stream>>>(vt, aH, oh);
    k4_final<<<dim3(Bn * Hn * 4), dim3(256), 0, stream>>>(vt, aW, oh, x, out);
}